// Round 4
// baseline (100.009 us; speedup 1.0000x reference)
//
#include <hip/hip_runtime.h>
#include <math.h>

// Exact EDT 1536x1536 (Meijster / scipy.distance_transform_edt semantics).
//
// Round-4 structure (3 kernels, was 4):
//  K1 edt_sum:   per (chunk=6 rows, col) compress bg flags into a 6-bit word
//                -> bits[NCH][CC] (u32). Mask is read exactly once (9.4 MB).
//  K2 edt_carry: per column, 256-step scan over chunk words to produce the
//                incoming down-carry CD / up-carry CU of every chunk.
//                a = ctz(w) (dist top->first bg), b = H-1-(31-clz(w)) (dist
//                bottom->last bg). Exact: in-chunk bg (<=5) always beats any
//                carry path (>=6): carry' = (b<BIG) ? b : min(carry+6, BIG).
//  K3 edt_strip: one block per 6-row strip. Carry-seeded down+up scan per
//                column into LDS g2[6][1536] (36 KB), barrier, then the exact
//                expanding-window min-plus with early exit (a candidate at
//                offset dk costs >= dk^2, so dk^2 >= best is final), sqrt,
//                write d_out. Removes the g2 global round-trip (19 MB).
// All values are integers < 2^24 -> fp32-exact (absmax 0.0 in rounds 2-3).

#define RR   1536
#define CC   1536
#define BIGF 3072.0f   // R + C, matches reference BIG
#define H    6         // strip height
#define NCH  256       // strips per column (H*NCH == RR)

__global__ __launch_bounds__(256) void edt_sum(
    const float* __restrict__ mask,
    unsigned* __restrict__ bits)   // [NCH][CC] 6-bit bg mask per chunk/col
{
    const int col = blockIdx.x * 256 + threadIdx.x;
    const int ch  = blockIdx.y;
    const float* __restrict__ p = mask + (size_t)(ch * H) * CC + col;
    unsigned w = 0;
    #pragma unroll
    for (int ri = 0; ri < H; ++ri) {
        if (p[ri * CC] == 0.0f) w |= (1u << ri);
    }
    bits[ch * CC + col] = w;
}

__global__ __launch_bounds__(256) void edt_carry(
    const unsigned* __restrict__ bits,
    float* __restrict__ CD,   // [NCH][CC] down-carry entering each chunk
    float* __restrict__ CU)   // [NCH][CC] up-carry entering each chunk
{
    const int tid = blockIdx.x * 256 + threadIdx.x;
    if (tid < CC) {
        const int col = tid;
        float carry = BIGF;                       // d[row -1]
        for (int c = 0; c < NCH; ++c) {
            CD[c * CC + col] = carry;
            unsigned w = bits[c * CC + col];
            unsigned hb = 31u - __builtin_clz(w | 1u);   // defined for w==0
            float b = w ? (float)(H - 1 - (int)hb) : BIGF;
            carry = (b < BIGF) ? b : fminf(carry + (float)H, BIGF);
        }
    } else if (tid < 2 * CC) {
        const int col = tid - CC;
        float carry = BIGF;                       // u[row RR]
        for (int c = NCH - 1; c >= 0; --c) {
            CU[c * CC + col] = carry;
            unsigned w = bits[c * CC + col];
            unsigned lb = __builtin_ctz(w | 0x80000000u); // defined for w==0
            float a = w ? (float)lb : BIGF;
            carry = (a < BIGF) ? a : fminf(carry + (float)H, BIGF);
        }
    }
}

__global__ __launch_bounds__(512) void edt_strip(
    const unsigned* __restrict__ bits,
    const float* __restrict__ CD,
    const float* __restrict__ CU,
    float* __restrict__ out)
{
    __shared__ float g2[H][CC];
    const int ch = blockIdx.x;
    const int t  = threadIdx.x;

    // ---- vertical fill (carry-seeded) into LDS ----
    #pragma unroll
    for (int m = 0; m < CC / 512; ++m) {
        const int c = t + m * 512;
        const unsigned w = bits[ch * CC + c];
        float d[H];
        float prev = CD[ch * CC + c];
        #pragma unroll
        for (int ri = 0; ri < H; ++ri) {
            bool bg = (w >> ri) & 1u;
            float dd = bg ? 0.0f : fminf(prev + 1.0f, BIGF);
            d[ri] = dd;
            prev = dd;
        }
        float up = CU[ch * CC + c];
        #pragma unroll
        for (int ri = H - 1; ri >= 0; --ri) {
            bool bg = (w >> ri) & 1u;
            float u = bg ? 0.0f : fminf(up + 1.0f, BIGF);
            up = u;
            float g = fminf(d[ri], u);
            g2[ri][c] = g * g;
        }
    }
    __syncthreads();

    // ---- exact early-exit min-plus per row, sqrt, store ----
    float* __restrict__ obase = out + (size_t)(ch * H) * CC;
    #pragma unroll
    for (int r = 0; r < H; ++r) {
        #pragma unroll
        for (int m = 0; m < CC / 512; ++m) {
            const int j = t + m * 512;
            float best = g2[r][j];
            int dk = 1;
            while ((float)(dk * dk) < best) {
                float dk2 = (float)(dk * dk);
                int kl = j - dk;
                int kr = j + dk;
                bool any = false;
                if (kl >= 0)  { best = fminf(best, g2[r][kl] + dk2); any = true; }
                if (kr < CC)  { best = fminf(best, g2[r][kr] + dk2); any = true; }
                if (!any) break;
                ++dk;
            }
            obase[r * CC + j] = sqrtf(best);
        }
    }
}

extern "C" void kernel_launch(void* const* d_in, const int* in_sizes, int n_in,
                              void* d_out, int out_size, void* d_ws, size_t ws_size,
                              hipStream_t stream) {
    const float* mask = (const float*)d_in[0];
    float* out = (float*)d_out;

    // workspace: bits (u32) + CD + CU, each NCH*CC elements = 4.7 MB total
    unsigned* bits = (unsigned*)d_ws;
    float* CD = (float*)(bits + NCH * CC);
    float* CU = CD + NCH * CC;

    edt_sum  <<<dim3(CC / 256, NCH), 256, 0, stream>>>(mask, bits);
    edt_carry<<<(2 * CC + 255) / 256, 256, 0, stream>>>(bits, CD, CU);
    edt_strip<<<NCH, 512, 0, stream>>>(bits, CD, CU, out);
}

// Round 5
// 81.113 us; speedup vs baseline: 1.2330x; 1.2330x over previous
//
#include <hip/hip_runtime.h>
#include <math.h>

// Exact EDT 1536x1536 (Meijster / scipy.distance_transform_edt semantics).
//
// Round-5 structure (3 kernels):
//  K1 edt_sum:   per (chunk=6 rows, col-pair) compress bg flags into 6-bit
//                words -> bits[NCH][CC] (u32). Mask read exactly once, float2.
//  K2 edt_carry: ONE BLOCK PER COLUMN (1536 x 256thr). The chunk-carry
//                recurrence carry' = min(b_c, carry+H) has constant shift H,
//                so it reduces to a prefix-min:
//                  CD[c] = min( premin_{k<c}(b_k - kH) + (c-1)H, BIG + cH )
//                  CU[c] = min( sufmin_{k>c}(a_k + kH) - (c+1)H, BIG + (NCH-1-c)H )
//                computed with an 8-step Hillis-Steele LDS min-scan (was a
//                256-step serial chain at 48 waves in round 4 -- the 30+ us
//                regression). Values >= BIG are downstream-equivalent to BIG
//                because the row fill clamps with fminf(prev+1, BIG).
//  K3 edt_strip: one block per 6-row strip. Carry-seeded down+up scan per
//                column into LDS g2[6][1536] (36 KB), barrier, exact
//                expanding-window min-plus with early exit (any candidate at
//                offset dk costs >= dk^2, so dk^2 >= best is final), sqrt out.
// All arithmetic on integers < 2^24 -> fp32-exact (absmax 0.0 rounds 2-4).

#define RR   1536
#define CC   1536
#define BIGF 3072.0f   // R + C, matches reference BIG
#define H    6         // strip/chunk height
#define NCH  256       // chunks per column (H*NCH == RR)

__global__ __launch_bounds__(256) void edt_sum(
    const float* __restrict__ mask,
    unsigned* __restrict__ bits)   // [NCH][CC] 6-bit bg mask per chunk/col
{
    const int col2 = blockIdx.x * 256 + threadIdx.x;   // pair index
    const int ch   = blockIdx.y;
    const float2* __restrict__ p =
        (const float2*)(mask + (size_t)(ch * H) * CC) + col2;
    unsigned w0 = 0, w1 = 0;
    #pragma unroll
    for (int ri = 0; ri < H; ++ri) {
        float2 m = p[ri * (CC / 2)];
        if (m.x == 0.0f) w0 |= (1u << ri);
        if (m.y == 0.0f) w1 |= (1u << ri);
    }
    bits[ch * CC + 2 * col2]     = w0;
    bits[ch * CC + 2 * col2 + 1] = w1;
}

__global__ __launch_bounds__(256) void edt_carry(
    const unsigned* __restrict__ bits,
    float* __restrict__ CD,   // [NCH][CC] down-carry entering each chunk
    float* __restrict__ CU)   // [NCH][CC] up-carry entering each chunk
{
    const int col = blockIdx.x;
    const int t   = threadIdx.x;            // chunk index
    __shared__ float Pm[NCH], Pn[NCH];

    unsigned w = bits[t * CC + col];        // uncoalesced but L2-resident
    float a, b;                             // a: top->first bg, b: bottom->last bg
    if (w) {
        a = (float)__builtin_ctz(w);
        b = (float)(H - 1 - (31 - __builtin_clz(w)));
    } else {
        a = BIGF; b = BIGF;
    }
    Pm[t]           = b - (float)(t * H);   // prefix-min operand (down)
    Pn[NCH - 1 - t] = a + (float)(t * H);   // reversed -> suffix-min (up)
    __syncthreads();

    #pragma unroll
    for (int off = 1; off < NCH; off <<= 1) {
        float vm, vn;
        if (t >= off) {
            vm = fminf(Pm[t], Pm[t - off]);
            vn = fminf(Pn[t], Pn[t - off]);
        }
        __syncthreads();
        if (t >= off) { Pm[t] = vm; Pn[t] = vn; }
        __syncthreads();
    }

    float cd = (t == 0) ? BIGF
             : fminf(Pm[t - 1] + (float)((t - 1) * H), BIGF + (float)(t * H));
    float cu = (t == NCH - 1) ? BIGF
             : fminf(Pn[NCH - 2 - t] - (float)((t + 1) * H),
                     BIGF + (float)((NCH - 1 - t) * H));
    CD[t * CC + col] = cd;
    CU[t * CC + col] = cu;
}

__global__ __launch_bounds__(512) void edt_strip(
    const unsigned* __restrict__ bits,
    const float* __restrict__ CD,
    const float* __restrict__ CU,
    float* __restrict__ out)
{
    __shared__ float g2[H][CC];
    const int ch = blockIdx.x;
    const int t  = threadIdx.x;

    // ---- vertical fill (carry-seeded) into LDS ----
    #pragma unroll
    for (int m = 0; m < CC / 512; ++m) {
        const int c = t + m * 512;
        const unsigned w = bits[ch * CC + c];
        float d[H];
        float prev = CD[ch * CC + c];
        #pragma unroll
        for (int ri = 0; ri < H; ++ri) {
            bool bg = (w >> ri) & 1u;
            float dd = bg ? 0.0f : fminf(prev + 1.0f, BIGF);
            d[ri] = dd;
            prev = dd;
        }
        float up = CU[ch * CC + c];
        #pragma unroll
        for (int ri = H - 1; ri >= 0; --ri) {
            bool bg = (w >> ri) & 1u;
            float u = bg ? 0.0f : fminf(up + 1.0f, BIGF);
            up = u;
            float g = fminf(d[ri], u);
            g2[ri][c] = g * g;
        }
    }
    __syncthreads();

    // ---- exact early-exit min-plus per row, sqrt, store ----
    float* __restrict__ obase = out + (size_t)(ch * H) * CC;
    #pragma unroll
    for (int r = 0; r < H; ++r) {
        #pragma unroll
        for (int m = 0; m < CC / 512; ++m) {
            const int j = t + m * 512;
            float best = g2[r][j];
            int dk = 1;
            while ((float)(dk * dk) < best) {
                float dk2 = (float)(dk * dk);
                int kl = j - dk;
                int kr = j + dk;
                bool any = false;
                if (kl >= 0)  { best = fminf(best, g2[r][kl] + dk2); any = true; }
                if (kr < CC)  { best = fminf(best, g2[r][kr] + dk2); any = true; }
                if (!any) break;
                ++dk;
            }
            obase[r * CC + j] = sqrtf(best);
        }
    }
}

extern "C" void kernel_launch(void* const* d_in, const int* in_sizes, int n_in,
                              void* d_out, int out_size, void* d_ws, size_t ws_size,
                              hipStream_t stream) {
    const float* mask = (const float*)d_in[0];
    float* out = (float*)d_out;

    // workspace: bits (u32) + CD + CU, each NCH*CC elements = 4.7 MB total
    unsigned* bits = (unsigned*)d_ws;
    float* CD = (float*)(bits + NCH * CC);
    float* CU = CD + NCH * CC;

    edt_sum  <<<dim3(CC / 512, NCH), 256, 0, stream>>>(mask, bits);
    edt_carry<<<CC, NCH, 0, stream>>>(bits, CD, CU);
    edt_strip<<<NCH, 512, 0, stream>>>(bits, CD, CU, out);
}

// Round 6
// 77.284 us; speedup vs baseline: 1.2940x; 1.0495x over previous
//
#include <hip/hip_runtime.h>
#include <math.h>

// Exact EDT 1536x1536 (Meijster / scipy.distance_transform_edt semantics).
//
// Round-6 change: round-5's fused edt_strip had only 256 blocks (1/CU,
// 2 waves/SIMD) and its latency phases didn't overlap -> ~55 us. Now each
// 6-row strip is split into 6 column-tiles of 256 with a +-128-col halo;
// the vertical fill is recomputed per tile (per-column independent given
// bits/CD/CU), so there is still no g2 global round-trip, but the grid is
// 1536 blocks (6/CU, 24 waves/CU).
//
//  K1 edt_sum:   per (chunk=6 rows, col-pair): 6-bit bg word -> bits[NCH][CC].
//  K2 edt_carry: one block per column; chunk-carry recurrence reduced to a
//                prefix-min (constant shift H) via 8-step Hillis-Steele scan.
//  K3 edt_strip: block = (strip ch, col-tile tx). Fill g2[6][512] in LDS
//                (tile + halo; out-of-grid halo = BIG^2 which never wins),
//                barrier, exact expanding-window min-plus with early exit
//                (candidate at offset dk costs >= dk^2, so dk^2 >= best is
//                final; dk capped at 128 = halo, >>max needed ~12 here),
//                sqrt, coalesced store.
// All arithmetic on integers < 2^24 -> fp32-exact (absmax 0.0 rounds 2-5).

#define RR   1536
#define CC   1536
#define BIGF 3072.0f          // R + C, matches reference BIG
#define BIG2 9437184.0f       // BIGF^2, exact in fp32 (< 2^24)
#define H    6                // strip height
#define NCH  256              // strips per column (H*NCH == RR)
#define TILE 256              // output columns per strip block
#define W    128              // halo columns each side
#define NT   (CC / TILE)      // col-tiles per strip

__global__ __launch_bounds__(256) void edt_sum(
    const float* __restrict__ mask,
    unsigned* __restrict__ bits)   // [NCH][CC] 6-bit bg mask per chunk/col
{
    const int col2 = blockIdx.x * 256 + threadIdx.x;   // pair index
    const int ch   = blockIdx.y;
    const float2* __restrict__ p =
        (const float2*)(mask + (size_t)(ch * H) * CC) + col2;
    unsigned w0 = 0, w1 = 0;
    #pragma unroll
    for (int ri = 0; ri < H; ++ri) {
        float2 m = p[ri * (CC / 2)];
        if (m.x == 0.0f) w0 |= (1u << ri);
        if (m.y == 0.0f) w1 |= (1u << ri);
    }
    bits[ch * CC + 2 * col2]     = w0;
    bits[ch * CC + 2 * col2 + 1] = w1;
}

__global__ __launch_bounds__(256) void edt_carry(
    const unsigned* __restrict__ bits,
    float* __restrict__ CD,   // [NCH][CC] down-carry entering each chunk
    float* __restrict__ CU)   // [NCH][CC] up-carry entering each chunk
{
    const int col = blockIdx.x;
    const int t   = threadIdx.x;            // chunk index
    __shared__ float Pm[NCH], Pn[NCH];

    unsigned w = bits[t * CC + col];        // gather, L2-resident (1.5 MB)
    float a, b;                             // a: top->first bg, b: bottom->last
    if (w) {
        a = (float)__builtin_ctz(w);
        b = (float)(H - 1 - (31 - __builtin_clz(w)));
    } else {
        a = BIGF; b = BIGF;
    }
    Pm[t]           = b - (float)(t * H);   // prefix-min operand (down)
    Pn[NCH - 1 - t] = a + (float)(t * H);   // reversed -> suffix-min (up)
    __syncthreads();

    #pragma unroll
    for (int off = 1; off < NCH; off <<= 1) {
        float vm, vn;
        if (t >= off) {
            vm = fminf(Pm[t], Pm[t - off]);
            vn = fminf(Pn[t], Pn[t - off]);
        }
        __syncthreads();
        if (t >= off) { Pm[t] = vm; Pn[t] = vn; }
        __syncthreads();
    }

    float cd = (t == 0) ? BIGF
             : fminf(Pm[t - 1] + (float)((t - 1) * H), BIGF + (float)(t * H));
    float cu = (t == NCH - 1) ? BIGF
             : fminf(Pn[NCH - 2 - t] - (float)((t + 1) * H),
                     BIGF + (float)((NCH - 1 - t) * H));
    CD[t * CC + col] = cd;
    CU[t * CC + col] = cu;
}

__global__ __launch_bounds__(256) void edt_strip(
    const unsigned* __restrict__ bits,
    const float* __restrict__ CD,
    const float* __restrict__ CU,
    float* __restrict__ out)
{
    __shared__ float g2[H][TILE + 2 * W];   // [6][512] = 12 KB
    const int ch = blockIdx.y;              // strip index
    const int tx = blockIdx.x;              // column tile index
    const int t  = threadIdx.x;
    const int c0 = tx * TILE - W;           // global col of LDS col 0

    // ---- vertical fill (carry-seeded) of tile + halo into LDS ----
    #pragma unroll
    for (int m = 0; m < 2; ++m) {
        const int lc = t + m * 256;         // LDS column
        const int c  = c0 + lc;             // global column
        if (c >= 0 && c < CC) {
            const unsigned w = bits[ch * CC + c];
            float d[H];
            float prev = CD[ch * CC + c];
            #pragma unroll
            for (int ri = 0; ri < H; ++ri) {
                bool bg = (w >> ri) & 1u;
                float dd = bg ? 0.0f : fminf(prev + 1.0f, BIGF);
                d[ri] = dd;
                prev = dd;
            }
            float up = CU[ch * CC + c];
            #pragma unroll
            for (int ri = H - 1; ri >= 0; --ri) {
                bool bg = (w >> ri) & 1u;
                float u = bg ? 0.0f : fminf(up + 1.0f, BIGF);
                up = u;
                float g = fminf(d[ri], u);
                g2[ri][lc] = g * g;
            }
        } else {
            #pragma unroll
            for (int ri = 0; ri < H; ++ri) g2[ri][lc] = BIG2;  // never wins
        }
    }
    __syncthreads();

    // ---- exact early-exit min-plus, sqrt, coalesced store ----
    float* __restrict__ obase = out + (size_t)(ch * H) * CC + tx * TILE;
    const int lj = t + W;                   // LDS index of this output col
    #pragma unroll
    for (int r = 0; r < H; ++r) {
        float best = g2[r][lj];
        int dk = 1;
        while (dk <= W && (float)(dk * dk) < best) {
            float dk2 = (float)(dk * dk);
            best = fminf(best, g2[r][lj - dk] + dk2);
            best = fminf(best, g2[r][lj + dk] + dk2);
            ++dk;
        }
        obase[r * CC + t] = sqrtf(best);
    }
}

extern "C" void kernel_launch(void* const* d_in, const int* in_sizes, int n_in,
                              void* d_out, int out_size, void* d_ws, size_t ws_size,
                              hipStream_t stream) {
    const float* mask = (const float*)d_in[0];
    float* out = (float*)d_out;

    // workspace: bits (u32) + CD + CU, each NCH*CC elements = 4.7 MB total
    unsigned* bits = (unsigned*)d_ws;
    float* CD = (float*)(bits + NCH * CC);
    float* CU = CD + NCH * CC;

    edt_sum  <<<dim3(CC / 512, NCH), 256, 0, stream>>>(mask, bits);
    edt_carry<<<CC, NCH, 0, stream>>>(bits, CD, CU);
    edt_strip<<<dim3(NT, NCH), 256, 0, stream>>>(bits, CD, CU, out);
}